// Round 9
// baseline (585.670 us; speedup 1.0000x reference)
//
#include <hip/hip_runtime.h>

#define B_  8
#define C_  256
#define C2_ 128
#define N_  4096
#define LOG2E 1.44269504088896f

typedef _Float16 f16;
typedef _Float16 f16x8 __attribute__((ext_vector_type(8)));
typedef float f32x4  __attribute__((ext_vector_type(4)));

// ---------------------------------------------------------------------------
// prep: cast W1/W2 to f16 once
// ---------------------------------------------------------------------------
__global__ __launch_bounds__(256)
void prep_kernel(const float* __restrict__ W1, const float* __restrict__ W2,
                 f16* __restrict__ w1h, f16* __restrict__ w2h)
{
  int i = blockIdx.x * 256 + threadIdx.x;   // grid 128 -> 32768
  w1h[i] = (f16)W1[i];
  w2h[i] = (f16)W2[i];
}

// ---------------------------------------------------------------------------
// conv1: Y[b,n,c2] = sum_c x[b,c,n]*W1[c2,c] + b1; dual layout Y + Yt.
// K=256 staged in 2 chunks of 128 -> LDS 32 KB -> 4 WG/CU. Tile 32n x 128c2.
// ---------------------------------------------------------------------------
__global__ __launch_bounds__(256, 4)
void conv1_kernel(const float* __restrict__ x,
                  const f16* __restrict__ w1h,
                  const float* __restrict__ b1,
                  f16* __restrict__ Y, f16* __restrict__ Yt)
{
  __shared__ __align__(16) char smem[32768];
  float* Xr = (float*)smem;            // [128 c][32 n] f32, float4-block XOR (16 KB)
  f16*   Ah = (f16*)(smem + 16384);    // [32 n][256 k] f16 XOR-8 (16 KB)
  f16*   T  = (f16*)smem;              // [128 c2][40 n] epilogue alias (10 KB)

  const int t = threadIdx.x;
  const int w = t >> 6, lane = t & 63, quad = lane >> 4, l16 = lane & 15;
  const int b = blockIdx.x, nt0 = blockIdx.y;

#pragma unroll 1
  for (int kc = 0; kc < 2; kc++) {
    // stage 128c x 32n fp32 (4 float4 loads in flight/thread)
#pragma unroll
    for (int pass = 0; pass < 4; pass++) {
      int c  = (t >> 3) + pass * 32;            // 0..127
      int n4 = t & 7;
      float4 v = *(const float4*)(x + ((long)(b * C_ + kc * 128 + c)) * N_ + nt0 * 32 + n4 * 4);
      *(float4*)(&Xr[c * 32 + (n4 ^ (c & 7)) * 4]) = v;
    }
    __syncthreads();
    // transpose+cvt into Ah [n][k] XOR-8
#pragma unroll
    for (int pass = 0; pass < 2; pass++) {
      int n   = t & 31;
      int kbl = (t >> 5) + pass * 8;            // 0..15
      f16x8 vh;
#pragma unroll
      for (int jj = 0; jj < 8; jj++) {
        int cc = kbl * 8 + jj;
        vh[jj] = (f16)Xr[cc * 32 + ((n >> 2) ^ (cc & 7)) * 4 + (n & 3)];
      }
      *(f16x8*)(&Ah[n * 256 + ((kc * 16 + kbl) ^ (n & 7)) * 8]) = vh;
    }
    __syncthreads();
  }

  f32x4 acc[2][2];
#pragma unroll
  for (int i = 0; i < 2; i++)
#pragma unroll
    for (int j = 0; j < 2; j++) acc[i][j] = (f32x4){0.f, 0.f, 0.f, 0.f};

#pragma unroll
  for (int ks = 0; ks < 8; ks++) {
    f16x8 bh[2];
#pragma unroll
    for (int nt = 0; nt < 2; nt++) {
      int c2 = w * 32 + nt * 16 + l16;
      bh[nt] = *(const f16x8*)(w1h + c2 * C_ + ks * 32 + quad * 8);
    }
#pragma unroll
    for (int mt = 0; mt < 2; mt++) {
      f16x8 ah = *(const f16x8*)(&Ah[(mt * 16 + l16) * 256 + (((ks * 4 + quad) ^ (l16 & 7))) * 8]);
#pragma unroll
      for (int nt = 0; nt < 2; nt++)
        acc[mt][nt] = __builtin_amdgcn_mfma_f32_16x16x32_f16(ah, bh[nt], acc[mt][nt], 0, 0, 0);
    }
  }

  // epilogue -> T[c2][n] (Xr region; all Xr reads ended at last barrier)
#pragma unroll
  for (int nt = 0; nt < 2; nt++) {
    int c2 = w * 32 + nt * 16 + l16;
    float bv = b1[c2];
#pragma unroll
    for (int mt = 0; mt < 2; mt++)
#pragma unroll
      for (int rg = 0; rg < 4; rg++) {
        int n = mt * 16 + quad * 4 + rg;
        T[c2 * 40 + n] = (f16)(acc[mt][nt][rg] + bv);
      }
  }
  __syncthreads();
  // Yt[c2][n]
#pragma unroll
  for (int pass = 0; pass < 2; pass++) {
    int r  = (t >> 2) + pass * 64;
    int c8 = (t & 3) * 8;
    f16x8 v = *(const f16x8*)(&T[r * 40 + c8]);
    *(f16x8*)(Yt + ((long)(b * C2_ + r)) * N_ + nt0 * 32 + c8) = v;
  }
  // Y[n][c2]
#pragma unroll
  for (int pass = 0; pass < 2; pass++) {
    int row = t & 31;
    int cg  = (t >> 5) + pass * 8;
    f16x8 v;
#pragma unroll
    for (int jj = 0; jj < 8; jj++) v[jj] = T[(cg * 8 + jj) * 40 + row];
    *(f16x8*)(Y + ((long)(b * N_ + nt0 * 32 + row)) * C2_ + cg * 8) = v;
  }
}

// ---------------------------------------------------------------------------
// attn: flash with fixed per-row max = |y_q|^2. BQ=128 (4 waves x 32 q),
// BK=64, split-K x gridDim.z (uneven split of 64 tiles). LDS 48 KB; at
// 3-4 splits the grid gives 3-4 WG/CU. Unnormalized O + row sums l out.
// ---------------------------------------------------------------------------
__global__ __launch_bounds__(256, 3)
void attn_kernel(const f16* __restrict__ Y, const f16* __restrict__ Yt,
                 f16* __restrict__ Op, float* __restrict__ ls)
{
  __shared__ f16 Ks[64 * 128];   // [key][d]  16B-block pos = (d>>3) ^ (key&15)
  __shared__ f16 Vs[128 * 64];   // [d][k]    pos = (k>>3) ^ (d&7)
  __shared__ f16 Ps[128 * 64];   // [q][k]    pos = (k>>3) ^ (q&7); prologue: nsq floats

  const int t = threadIdx.x;
  const int w = t >> 6, lane = t & 63, quad = lane >> 4, l16 = lane & 15;
  const int b = blockIdx.x, qt = blockIdx.y, s = blockIdx.z;
  const int ns = gridDim.z;
  const int per = 64 / ns, rem = 64 % ns;
  const int cnt = per + (s < rem ? 1 : 0);
  const int st  = s * per + (s < rem ? s : rem);
  const int kbase0 = st * 64;

  const f16* Yb  = Y  + (long)b * N_ * C2_;
  const f16* Ytb = Yt + (long)b * C2_ * N_;

  // Q frags (resident all kernel)
  f16x8 qf[2][4];
#pragma unroll
  for (int mt = 0; mt < 2; mt++)
#pragma unroll
    for (int ks = 0; ks < 4; ks++)
      qf[mt][ks] = *(const f16x8*)(Yb + (long)(qt * 128 + w * 32 + mt * 16 + l16) * C2_ + ks * 32 + quad * 8);

  // per-row |y_q|^2 into Ps-as-float
  {
    float* nsqf = (float*)Ps;
    int r = t >> 1, half = t & 1;
    float ss = 0.f;
#pragma unroll
    for (int j = 0; j < 8; j++) {
      f16x8 v = *(const f16x8*)(Yb + (long)(qt * 128 + r) * C2_ + half * 64 + j * 8);
#pragma unroll
      for (int e = 0; e < 8; e++) { float f = (float)v[e]; ss = fmaf(f, f, ss); }
    }
    ss += __shfl_xor(ss, 1);
    if (!(t & 1)) nsqf[r] = ss;
  }

  // prologue: stage tile 0 of this split
#pragma unroll
  for (int pass = 0; pass < 4; pass++) {
    int r = (t >> 4) + pass * 16;
    f16x8 kv = *(const f16x8*)(Yb + (long)(kbase0 + r) * C2_ + (t & 15) * 8);
    *(f16x8*)(&Ks[r * 128 + (((t & 15)) ^ (r & 15)) * 8]) = kv;
  }
#pragma unroll
  for (int pass = 0; pass < 4; pass++) {
    int d = (t >> 3) + pass * 32;
    f16x8 vv = *(const f16x8*)(Ytb + (long)d * N_ + kbase0 + (t & 7) * 8);
    *(f16x8*)(&Vs[d * 64 + (((t & 7)) ^ (d & 7)) * 8]) = vv;
  }
  __syncthreads();

  float myns[2][4];
  {
    const float* nsqf = (const float*)Ps;
#pragma unroll
    for (int mt = 0; mt < 2; mt++)
#pragma unroll
      for (int rg = 0; rg < 4; rg++)
        myns[mt][rg] = nsqf[w * 32 + mt * 16 + quad * 4 + rg] * LOG2E;
  }
  __syncthreads();   // nsq reads done before Ps reuse

  f16x8 ones;
#pragma unroll
  for (int j = 0; j < 8; j++) ones[j] = (f16)1.0f;

  f32x4 Oa[2][8];
#pragma unroll
  for (int i = 0; i < 2; i++)
#pragma unroll
    for (int j = 0; j < 8; j++) Oa[i][j] = (f32x4){0.f, 0.f, 0.f, 0.f};
  f32x4 lac[2] = {(f32x4){0.f,0.f,0.f,0.f}, (f32x4){0.f,0.f,0.f,0.f}};

#pragma unroll 1
  for (int kt = 0; kt < cnt; kt++) {
    // prefetch next tile into registers
    f16x8 stK[4], stV[4];
    if (kt + 1 < cnt) {
      int nb = kbase0 + (kt + 1) * 64;
#pragma unroll
      for (int pass = 0; pass < 4; pass++)
        stK[pass] = *(const f16x8*)(Yb + (long)(nb + (t >> 4) + pass * 16) * C2_ + (t & 15) * 8);
#pragma unroll
      for (int pass = 0; pass < 4; pass++)
        stV[pass] = *(const f16x8*)(Ytb + (long)((t >> 3) + pass * 32) * N_ + nb + (t & 7) * 8);
    }

    // S = Q K^T (fp32)
    f32x4 S[2][4];
#pragma unroll
    for (int i = 0; i < 2; i++)
#pragma unroll
      for (int j = 0; j < 4; j++) S[i][j] = (f32x4){0.f, 0.f, 0.f, 0.f};
#pragma unroll
    for (int ks = 0; ks < 4; ks++) {
      f16x8 bfr[4];
#pragma unroll
      for (int nt = 0; nt < 4; nt++)
        bfr[nt] = *(const f16x8*)(&Ks[(nt * 16 + l16) * 128 + (((ks * 4 + quad) ^ l16)) * 8]);
#pragma unroll
      for (int mt = 0; mt < 2; mt++)
#pragma unroll
        for (int nt = 0; nt < 4; nt++)
          S[mt][nt] = __builtin_amdgcn_mfma_f32_16x16x32_f16(qf[mt][ks], bfr[nt], S[mt][nt], 0, 0, 0);
    }

    // fixed-max exp + P write (wave-private rows)
#pragma unroll
    for (int mt = 0; mt < 2; mt++)
#pragma unroll
      for (int rg = 0; rg < 4; rg++) {
        float nm = myns[mt][rg];
        int r = w * 32 + mt * 16 + quad * 4 + rg;
#pragma unroll
        for (int nt = 0; nt < 4; nt++) {
          float p = exp2f(fminf(fmaf(S[mt][nt][rg], LOG2E, -nm), 11.0f));
          int col = nt * 16 + l16;
          Ps[r * 64 + (((col >> 3) ^ (r & 7))) * 8 + (col & 7)] = (f16)p;
        }
      }

    // O += P V ; l += P 1
#pragma unroll
    for (int ks2 = 0; ks2 < 2; ks2++) {
      f16x8 vb[8];
#pragma unroll
      for (int dt = 0; dt < 8; dt++)
        vb[dt] = *(const f16x8*)(&Vs[(dt * 16 + l16) * 64 + (((ks2 * 4 + quad) ^ (l16 & 7))) * 8]);
      f16x8 pa[2];
#pragma unroll
      for (int mt = 0; mt < 2; mt++)
        pa[mt] = *(const f16x8*)(&Ps[(w * 32 + mt * 16 + l16) * 64 + (((ks2 * 4 + quad) ^ (l16 & 7))) * 8]);
#pragma unroll
      for (int mt = 0; mt < 2; mt++) {
#pragma unroll
        for (int dt = 0; dt < 8; dt++)
          Oa[mt][dt] = __builtin_amdgcn_mfma_f32_16x16x32_f16(pa[mt], vb[dt], Oa[mt][dt], 0, 0, 0);
        lac[mt] = __builtin_amdgcn_mfma_f32_16x16x32_f16(pa[mt], ones, lac[mt], 0, 0, 0);
      }
    }

    __syncthreads();   // Ks/Vs reads done
    if (kt + 1 < cnt) {
#pragma unroll
      for (int pass = 0; pass < 4; pass++) {
        int r = (t >> 4) + pass * 16;
        *(f16x8*)(&Ks[r * 128 + (((t & 15)) ^ (r & 15)) * 8]) = stK[pass];
      }
#pragma unroll
      for (int pass = 0; pass < 4; pass++) {
        int d = (t >> 3) + pass * 32;
        *(f16x8*)(&Vs[d * 64 + (((t & 7)) ^ (d & 7)) * 8]) = stV[pass];
      }
    }
    __syncthreads();
  }

  // epilogue: unnormalized O + row sums l
  const long rbase = ((long)s * B_ + b) * N_ + qt * 128;
#pragma unroll
  for (int mt = 0; mt < 2; mt++)
#pragma unroll
    for (int rg = 0; rg < 4; rg++) {
      int r = w * 32 + mt * 16 + quad * 4 + rg;
#pragma unroll
      for (int dt = 0; dt < 8; dt++)
        Op[(rbase + r) * C2_ + dt * 16 + l16] = (f16)Oa[mt][dt][rg];
      if (l16 == 0) ls[rbase + r] = lac[mt][rg];
    }
}

// ---------------------------------------------------------------------------
// conv2 + fused n-way split-combine + scale + residual. Grid (8, 64, 2).
// ---------------------------------------------------------------------------
__global__ __launch_bounds__(256, 4)
void conv2_kernel(const f16* __restrict__ Op, const float* __restrict__ ls,
                  const f16* __restrict__ w2h,
                  const float* __restrict__ b2,
                  const float* __restrict__ scale,
                  const float* __restrict__ x,
                  float* __restrict__ out, int ns)
{
  __shared__ f16 Or[128 * 72];      // [j][p_local]
  __shared__ f16 Bsw[64 * 128];     // [p][j] XOR-16
  __shared__ float invL[128];

  const int t = threadIdx.x;
  const int w = t >> 6, lane = t & 63, quad = lane >> 4, l16 = lane & 15;
  const int b = blockIdx.x, pt = blockIdx.y, oh = blockIdx.z;

  if (t < 128) {
    int q = t * 32 + (pt >> 1);
    float l = 0.f;
#pragma unroll 1
    for (int ss = 0; ss < ns; ss++) l += ls[(long)ss * 32768 + (long)b * N_ + q];
    invL[t] = 1.0f / fmaxf(l, 1e-20f);
  }
  __syncthreads();

#pragma unroll
  for (int pass = 0; pass < 4; pass++) {
    int j = (t >> 3) + pass * 32;            // 0..127
    int c8 = (t & 7) * 8;                    // p_local
    float s8[8] = {0.f,0.f,0.f,0.f,0.f,0.f,0.f,0.f};
#pragma unroll 1
    for (int ss = 0; ss < ns; ss++) {
      f16x8 a = *(const f16x8*)(Op + ((long)ss * B_ + b) * ((long)N_ * C2_) + (long)j * N_ + pt * 64 + c8);
#pragma unroll
      for (int jj = 0; jj < 8; jj++) s8[jj] += (float)a[jj];
    }
    float iv = invL[j];
    f16x8 r;
#pragma unroll
    for (int jj = 0; jj < 8; jj++) r[jj] = (f16)(s8[jj] * iv);
    *(f16x8*)(&Or[j * 72 + c8]) = r;
  }
  __syncthreads();
#pragma unroll
  for (int pass = 0; pass < 4; pass++) {
    int p = t & 63;
    int q = (t >> 6) + pass * 4;             // j-block 0..15
    f16x8 vv;
#pragma unroll
    for (int jj = 0; jj < 8; jj++) vv[jj] = Or[(q * 8 + jj) * 72 + p];
    *(f16x8*)(&Bsw[p * 128 + ((q ^ (p & 15))) * 8]) = vv;
  }
  __syncthreads();

  f32x4 acc[2][4];
#pragma unroll
  for (int i = 0; i < 2; i++)
#pragma unroll
    for (int j = 0; j < 4; j++) acc[i][j] = (f32x4){0.f, 0.f, 0.f, 0.f};

#pragma unroll
  for (int ks = 0; ks < 4; ks++) {
    f16x8 bfr[4];
#pragma unroll
    for (int nt = 0; nt < 4; nt++)
      bfr[nt] = *(const f16x8*)(&Bsw[(nt * 16 + l16) * 128 + (((ks * 4 + quad) ^ l16)) * 8]);
#pragma unroll
    for (int mt = 0; mt < 2; mt++) {
      int o = oh * 128 + w * 32 + mt * 16 + l16;
      f16x8 ah = *(const f16x8*)(w2h + o * C2_ + ks * 32 + quad * 8);
#pragma unroll
      for (int nt = 0; nt < 4; nt++)
        acc[mt][nt] = __builtin_amdgcn_mfma_f32_16x16x32_f16(ah, bfr[nt], acc[mt][nt], 0, 0, 0);
    }
  }
#pragma unroll
  for (int mt = 0; mt < 2; mt++)
#pragma unroll
    for (int rg = 0; rg < 4; rg++) {
      int o = oh * 128 + w * 32 + mt * 16 + quad * 4 + rg;
      float so = scale[o], bo = b2[o];
#pragma unroll
      for (int nt = 0; nt < 4; nt++) {
        int p = pt * 64 + nt * 16 + l16;
        long xo = ((long)b * C_ + o) * N_ + p;
        out[xo] = (acc[mt][nt][rg] + bo) * so + x[xo];
      }
    }
}

extern "C" void kernel_launch(void* const* d_in, const int* in_sizes, int n_in,
                              void* d_out, int out_size, void* d_ws, size_t ws_size,
                              hipStream_t stream) {
  const float* x     = (const float*)d_in[0];
  const float* W1    = (const float*)d_in[1];
  const float* b1    = (const float*)d_in[2];
  const float* W2    = (const float*)d_in[3];
  const float* b2    = (const float*)d_in[4];
  const float* scale = (const float*)d_in[5];
  float* outp = (float*)d_out;

  const size_t NE = (size_t)B_ * N_ * C2_;       // 4,194,304
  f16* Y    = (f16*)d_ws;                        // 8 MiB
  f16* Yt   = Y + NE;                            // 8 MiB
  f16* w1h  = Yt + NE;                           // 64 KiB
  f16* w2h  = w1h + 32768;                       // 64 KiB
  float* ls = (float*)(w2h + 32768);             // up to 4 x 32768 f32 (512 KiB)
  f16* Op   = (f16*)(ls + 4 * 32768);            // ns x 8 MiB split partials

  // choose split count from workspace size (constant across calls)
  size_t fixed = (size_t)((char*)Op - (char*)d_ws);
  int ns = 2;
  if (ws_size >= fixed + 4 * NE * sizeof(f16)) ns = 4;
  else if (ws_size >= fixed + 3 * NE * sizeof(f16)) ns = 3;

  prep_kernel <<<dim3(128),       dim3(256), 0, stream>>>(W1, W2, w1h, w2h);
  conv1_kernel<<<dim3(8, 128),    dim3(256), 0, stream>>>(x, w1h, b1, Y, Yt);
  attn_kernel <<<dim3(8, 32, ns), dim3(256), 0, stream>>>(Y, Yt, Op, ls);
  conv2_kernel<<<dim3(8, 64, 2),  dim3(256), 0, stream>>>(Op, ls, w2h, b2, scale, x, outp, ns);
}

// Round 10
// 226.703 us; speedup vs baseline: 2.5834x; 2.5834x over previous
//
#include <hip/hip_runtime.h>

#define B_  8
#define C_  256
#define C2_ 128
#define N_  4096
#define LOG2E 1.44269504088896f

typedef _Float16 f16;
typedef _Float16 f16x8 __attribute__((ext_vector_type(8)));
typedef float f32x4  __attribute__((ext_vector_type(4)));

// ---------------------------------------------------------------------------
// prep: cast W1/W2 to f16 once
// ---------------------------------------------------------------------------
__global__ __launch_bounds__(256)
void prep_kernel(const float* __restrict__ W1, const float* __restrict__ W2,
                 f16* __restrict__ w1h, f16* __restrict__ w2h)
{
  int i = blockIdx.x * 256 + threadIdx.x;   // grid 128 -> 32768
  w1h[i] = (f16)W1[i];
  w2h[i] = (f16)W2[i];
}

// ---------------------------------------------------------------------------
// conv1: Y[b,n,c2] = sum_c x[b,c,n]*W1[c2,c] + b1; dual layout Y + Yt.
// K=256 staged in 2 chunks of 128 -> LDS 32 KB -> 4 WG/CU. Tile 32n x 128c2.
// ---------------------------------------------------------------------------
__global__ __launch_bounds__(256, 4)
void conv1_kernel(const float* __restrict__ x,
                  const f16* __restrict__ w1h,
                  const float* __restrict__ b1,
                  f16* __restrict__ Y, f16* __restrict__ Yt)
{
  __shared__ __align__(16) char smem[32768];
  float* Xr = (float*)smem;            // [128 c][32 n] f32, float4-block XOR (16 KB)
  f16*   Ah = (f16*)(smem + 16384);    // [32 n][256 k] f16 XOR-8 (16 KB)
  f16*   T  = (f16*)smem;              // [128 c2][40 n] epilogue alias (10 KB)

  const int t = threadIdx.x;
  const int w = t >> 6, lane = t & 63, quad = lane >> 4, l16 = lane & 15;
  const int b = blockIdx.x, nt0 = blockIdx.y;

#pragma unroll 1
  for (int kc = 0; kc < 2; kc++) {
    // stage 128c x 32n fp32 (4 float4 loads in flight/thread)
#pragma unroll
    for (int pass = 0; pass < 4; pass++) {
      int c  = (t >> 3) + pass * 32;            // 0..127
      int n4 = t & 7;
      float4 v = *(const float4*)(x + ((long)(b * C_ + kc * 128 + c)) * N_ + nt0 * 32 + n4 * 4);
      *(float4*)(&Xr[c * 32 + (n4 ^ (c & 7)) * 4]) = v;
    }
    __syncthreads();
    // transpose+cvt into Ah [n][k] XOR-8
#pragma unroll
    for (int pass = 0; pass < 2; pass++) {
      int n   = t & 31;
      int kbl = (t >> 5) + pass * 8;            // 0..15
      f16x8 vh;
#pragma unroll
      for (int jj = 0; jj < 8; jj++) {
        int cc = kbl * 8 + jj;
        vh[jj] = (f16)Xr[cc * 32 + ((n >> 2) ^ (cc & 7)) * 4 + (n & 3)];
      }
      *(f16x8*)(&Ah[n * 256 + ((kc * 16 + kbl) ^ (n & 7)) * 8]) = vh;
    }
    __syncthreads();
  }

  f32x4 acc[2][2];
#pragma unroll
  for (int i = 0; i < 2; i++)
#pragma unroll
    for (int j = 0; j < 2; j++) acc[i][j] = (f32x4){0.f, 0.f, 0.f, 0.f};

#pragma unroll
  for (int ks = 0; ks < 8; ks++) {
    f16x8 bh[2];
#pragma unroll
    for (int nt = 0; nt < 2; nt++) {
      int c2 = w * 32 + nt * 16 + l16;
      bh[nt] = *(const f16x8*)(w1h + c2 * C_ + ks * 32 + quad * 8);
    }
#pragma unroll
    for (int mt = 0; mt < 2; mt++) {
      f16x8 ah = *(const f16x8*)(&Ah[(mt * 16 + l16) * 256 + (((ks * 4 + quad) ^ (l16 & 7))) * 8]);
#pragma unroll
      for (int nt = 0; nt < 2; nt++)
        acc[mt][nt] = __builtin_amdgcn_mfma_f32_16x16x32_f16(ah, bh[nt], acc[mt][nt], 0, 0, 0);
    }
  }

  // epilogue -> T[c2][n] (Xr region; all Xr reads ended at last barrier)
#pragma unroll
  for (int nt = 0; nt < 2; nt++) {
    int c2 = w * 32 + nt * 16 + l16;
    float bv = b1[c2];
#pragma unroll
    for (int mt = 0; mt < 2; mt++)
#pragma unroll
      for (int rg = 0; rg < 4; rg++) {
        int n = mt * 16 + quad * 4 + rg;
        T[c2 * 40 + n] = (f16)(acc[mt][nt][rg] + bv);
      }
  }
  __syncthreads();
  // Yt[c2][n]
#pragma unroll
  for (int pass = 0; pass < 2; pass++) {
    int r  = (t >> 2) + pass * 64;
    int c8 = (t & 3) * 8;
    f16x8 v = *(const f16x8*)(&T[r * 40 + c8]);
    *(f16x8*)(Yt + ((long)(b * C2_ + r)) * N_ + nt0 * 32 + c8) = v;
  }
  // Y[n][c2]
#pragma unroll
  for (int pass = 0; pass < 2; pass++) {
    int row = t & 31;
    int cg  = (t >> 5) + pass * 8;
    f16x8 v;
#pragma unroll
    for (int jj = 0; jj < 8; jj++) v[jj] = T[(cg * 8 + jj) * 40 + row];
    *(f16x8*)(Y + ((long)(b * N_ + nt0 * 32 + row)) * C2_ + cg * 8) = v;
  }
}

// ---------------------------------------------------------------------------
// attn: flash with fixed per-row max = |y_q|^2. BQ=128 (4 waves x 32 q),
// BK=64, split-K x gridDim.z. LDS 48 KB -> 3 WG/CU when grid >= 768.
// __launch_bounds__ 2nd arg MUST stay 2: forcing 3 caps VGPR~85 and spills
// the prefetch registers to scratch (R9: 0.5 GB/way scratch traffic, 4.3x
// slower). Occupancy comes from grid+LDS, not the allocator bound.
// ---------------------------------------------------------------------------
__global__ __launch_bounds__(256, 2)
void attn_kernel(const f16* __restrict__ Y, const f16* __restrict__ Yt,
                 f16* __restrict__ Op, float* __restrict__ ls)
{
  __shared__ f16 Ks[64 * 128];   // [key][d]  16B-block pos = (d>>3) ^ (key&15)
  __shared__ f16 Vs[128 * 64];   // [d][k]    pos = (k>>3) ^ (d&7)
  __shared__ f16 Ps[128 * 64];   // [q][k]    pos = (k>>3) ^ (q&7); prologue: nsq floats

  const int t = threadIdx.x;
  const int w = t >> 6, lane = t & 63, quad = lane >> 4, l16 = lane & 15;
  const int b = blockIdx.x, qt = blockIdx.y, s = blockIdx.z;
  const int ns = gridDim.z;
  const int per = 64 / ns, rem = 64 % ns;
  const int cnt = per + (s < rem ? 1 : 0);
  const int st  = s * per + (s < rem ? s : rem);
  const int kbase0 = st * 64;

  const f16* Yb  = Y  + (long)b * N_ * C2_;
  const f16* Ytb = Yt + (long)b * C2_ * N_;

  // Q frags (resident all kernel)
  f16x8 qf[2][4];
#pragma unroll
  for (int mt = 0; mt < 2; mt++)
#pragma unroll
    for (int ks = 0; ks < 4; ks++)
      qf[mt][ks] = *(const f16x8*)(Yb + (long)(qt * 128 + w * 32 + mt * 16 + l16) * C2_ + ks * 32 + quad * 8);

  // per-row |y_q|^2 into Ps-as-float
  {
    float* nsqf = (float*)Ps;
    int r = t >> 1, half = t & 1;
    float ss = 0.f;
#pragma unroll
    for (int j = 0; j < 8; j++) {
      f16x8 v = *(const f16x8*)(Yb + (long)(qt * 128 + r) * C2_ + half * 64 + j * 8);
#pragma unroll
      for (int e = 0; e < 8; e++) { float f = (float)v[e]; ss = fmaf(f, f, ss); }
    }
    ss += __shfl_xor(ss, 1);
    if (!(t & 1)) nsqf[r] = ss;
  }

  // prologue: stage tile 0 of this split
#pragma unroll
  for (int pass = 0; pass < 4; pass++) {
    int r = (t >> 4) + pass * 16;
    f16x8 kv = *(const f16x8*)(Yb + (long)(kbase0 + r) * C2_ + (t & 15) * 8);
    *(f16x8*)(&Ks[r * 128 + (((t & 15)) ^ (r & 15)) * 8]) = kv;
  }
#pragma unroll
  for (int pass = 0; pass < 4; pass++) {
    int d = (t >> 3) + pass * 32;
    f16x8 vv = *(const f16x8*)(Ytb + (long)d * N_ + kbase0 + (t & 7) * 8);
    *(f16x8*)(&Vs[d * 64 + (((t & 7)) ^ (d & 7)) * 8]) = vv;
  }
  __syncthreads();

  float myns[2][4];
  {
    const float* nsqf = (const float*)Ps;
#pragma unroll
    for (int mt = 0; mt < 2; mt++)
#pragma unroll
      for (int rg = 0; rg < 4; rg++)
        myns[mt][rg] = nsqf[w * 32 + mt * 16 + quad * 4 + rg] * LOG2E;
  }
  __syncthreads();   // nsq reads done before Ps reuse

  f16x8 ones;
#pragma unroll
  for (int j = 0; j < 8; j++) ones[j] = (f16)1.0f;

  f32x4 Oa[2][8];
#pragma unroll
  for (int i = 0; i < 2; i++)
#pragma unroll
    for (int j = 0; j < 8; j++) Oa[i][j] = (f32x4){0.f, 0.f, 0.f, 0.f};
  f32x4 lac[2] = {(f32x4){0.f,0.f,0.f,0.f}, (f32x4){0.f,0.f,0.f,0.f}};

#pragma unroll 1
  for (int kt = 0; kt < cnt; kt++) {
    // prefetch next tile into registers
    f16x8 stK[4], stV[4];
    if (kt + 1 < cnt) {
      int nb = kbase0 + (kt + 1) * 64;
#pragma unroll
      for (int pass = 0; pass < 4; pass++)
        stK[pass] = *(const f16x8*)(Yb + (long)(nb + (t >> 4) + pass * 16) * C2_ + (t & 15) * 8);
#pragma unroll
      for (int pass = 0; pass < 4; pass++)
        stV[pass] = *(const f16x8*)(Ytb + (long)((t >> 3) + pass * 32) * N_ + nb + (t & 7) * 8);
    }

    // S = Q K^T (fp32)
    f32x4 S[2][4];
#pragma unroll
    for (int i = 0; i < 2; i++)
#pragma unroll
      for (int j = 0; j < 4; j++) S[i][j] = (f32x4){0.f, 0.f, 0.f, 0.f};
#pragma unroll
    for (int ks = 0; ks < 4; ks++) {
      f16x8 bfr[4];
#pragma unroll
      for (int nt = 0; nt < 4; nt++)
        bfr[nt] = *(const f16x8*)(&Ks[(nt * 16 + l16) * 128 + (((ks * 4 + quad) ^ l16)) * 8]);
#pragma unroll
      for (int mt = 0; mt < 2; mt++)
#pragma unroll
        for (int nt = 0; nt < 4; nt++)
          S[mt][nt] = __builtin_amdgcn_mfma_f32_16x16x32_f16(qf[mt][ks], bfr[nt], S[mt][nt], 0, 0, 0);
    }

    // fixed-max exp + P write (wave-private rows)
#pragma unroll
    for (int mt = 0; mt < 2; mt++)
#pragma unroll
      for (int rg = 0; rg < 4; rg++) {
        float nm = myns[mt][rg];
        int r = w * 32 + mt * 16 + quad * 4 + rg;
#pragma unroll
        for (int nt = 0; nt < 4; nt++) {
          float p = exp2f(fminf(fmaf(S[mt][nt][rg], LOG2E, -nm), 11.0f));
          int col = nt * 16 + l16;
          Ps[r * 64 + (((col >> 3) ^ (r & 7))) * 8 + (col & 7)] = (f16)p;
        }
      }

    // O += P V ; l += P 1
#pragma unroll
    for (int ks2 = 0; ks2 < 2; ks2++) {
      f16x8 vb[8];
#pragma unroll
      for (int dt = 0; dt < 8; dt++)
        vb[dt] = *(const f16x8*)(&Vs[(dt * 16 + l16) * 64 + (((ks2 * 4 + quad) ^ (l16 & 7))) * 8]);
      f16x8 pa[2];
#pragma unroll
      for (int mt = 0; mt < 2; mt++)
        pa[mt] = *(const f16x8*)(&Ps[(w * 32 + mt * 16 + l16) * 64 + (((ks2 * 4 + quad) ^ (l16 & 7))) * 8]);
#pragma unroll
      for (int mt = 0; mt < 2; mt++) {
#pragma unroll
        for (int dt = 0; dt < 8; dt++)
          Oa[mt][dt] = __builtin_amdgcn_mfma_f32_16x16x32_f16(pa[mt], vb[dt], Oa[mt][dt], 0, 0, 0);
        lac[mt] = __builtin_amdgcn_mfma_f32_16x16x32_f16(pa[mt], ones, lac[mt], 0, 0, 0);
      }
    }

    __syncthreads();   // Ks/Vs reads done
    if (kt + 1 < cnt) {
#pragma unroll
      for (int pass = 0; pass < 4; pass++) {
        int r = (t >> 4) + pass * 16;
        *(f16x8*)(&Ks[r * 128 + (((t & 15)) ^ (r & 15)) * 8]) = stK[pass];
      }
#pragma unroll
      for (int pass = 0; pass < 4; pass++) {
        int d = (t >> 3) + pass * 32;
        *(f16x8*)(&Vs[d * 64 + (((t & 7)) ^ (d & 7)) * 8]) = stV[pass];
      }
    }
    __syncthreads();
  }

  // epilogue: unnormalized O + row sums l
  const long rbase = ((long)s * B_ + b) * N_ + qt * 128;
#pragma unroll
  for (int mt = 0; mt < 2; mt++)
#pragma unroll
    for (int rg = 0; rg < 4; rg++) {
      int r = w * 32 + mt * 16 + quad * 4 + rg;
#pragma unroll
      for (int dt = 0; dt < 8; dt++)
        Op[(rbase + r) * C2_ + dt * 16 + l16] = (f16)Oa[mt][dt][rg];
      if (l16 == 0) ls[rbase + r] = lac[mt][rg];
    }
}

// ---------------------------------------------------------------------------
// conv2 + fused n-way split-combine + scale + residual. Grid (8, 64, 2).
// ---------------------------------------------------------------------------
__global__ __launch_bounds__(256, 4)
void conv2_kernel(const f16* __restrict__ Op, const float* __restrict__ ls,
                  const f16* __restrict__ w2h,
                  const float* __restrict__ b2,
                  const float* __restrict__ scale,
                  const float* __restrict__ x,
                  float* __restrict__ out, int ns)
{
  __shared__ f16 Or[128 * 72];      // [j][p_local]
  __shared__ f16 Bsw[64 * 128];     // [p][j] XOR-16
  __shared__ float invL[128];

  const int t = threadIdx.x;
  const int w = t >> 6, lane = t & 63, quad = lane >> 4, l16 = lane & 15;
  const int b = blockIdx.x, pt = blockIdx.y, oh = blockIdx.z;

  if (t < 128) {
    int q = t * 32 + (pt >> 1);
    float l = 0.f;
#pragma unroll 1
    for (int ss = 0; ss < ns; ss++) l += ls[(long)ss * 32768 + (long)b * N_ + q];
    invL[t] = 1.0f / fmaxf(l, 1e-20f);
  }
  __syncthreads();

#pragma unroll
  for (int pass = 0; pass < 4; pass++) {
    int j = (t >> 3) + pass * 32;            // 0..127
    int c8 = (t & 7) * 8;                    // p_local
    float s8[8] = {0.f,0.f,0.f,0.f,0.f,0.f,0.f,0.f};
#pragma unroll 1
    for (int ss = 0; ss < ns; ss++) {
      f16x8 a = *(const f16x8*)(Op + ((long)ss * B_ + b) * ((long)N_ * C2_) + (long)j * N_ + pt * 64 + c8);
#pragma unroll
      for (int jj = 0; jj < 8; jj++) s8[jj] += (float)a[jj];
    }
    float iv = invL[j];
    f16x8 r;
#pragma unroll
    for (int jj = 0; jj < 8; jj++) r[jj] = (f16)(s8[jj] * iv);
    *(f16x8*)(&Or[j * 72 + c8]) = r;
  }
  __syncthreads();
#pragma unroll
  for (int pass = 0; pass < 4; pass++) {
    int p = t & 63;
    int q = (t >> 6) + pass * 4;             // j-block 0..15
    f16x8 vv;
#pragma unroll
    for (int jj = 0; jj < 8; jj++) vv[jj] = Or[(q * 8 + jj) * 72 + p];
    *(f16x8*)(&Bsw[p * 128 + ((q ^ (p & 15))) * 8]) = vv;
  }
  __syncthreads();

  f32x4 acc[2][4];
#pragma unroll
  for (int i = 0; i < 2; i++)
#pragma unroll
    for (int j = 0; j < 4; j++) acc[i][j] = (f32x4){0.f, 0.f, 0.f, 0.f};

#pragma unroll
  for (int ks = 0; ks < 4; ks++) {
    f16x8 bfr[4];
#pragma unroll
    for (int nt = 0; nt < 4; nt++)
      bfr[nt] = *(const f16x8*)(&Bsw[(nt * 16 + l16) * 128 + (((ks * 4 + quad) ^ l16)) * 8]);
#pragma unroll
    for (int mt = 0; mt < 2; mt++) {
      int o = oh * 128 + w * 32 + mt * 16 + l16;
      f16x8 ah = *(const f16x8*)(w2h + o * C2_ + ks * 32 + quad * 8);
#pragma unroll
      for (int nt = 0; nt < 4; nt++)
        acc[mt][nt] = __builtin_amdgcn_mfma_f32_16x16x32_f16(ah, bfr[nt], acc[mt][nt], 0, 0, 0);
    }
  }
#pragma unroll
  for (int mt = 0; mt < 2; mt++)
#pragma unroll
    for (int rg = 0; rg < 4; rg++) {
      int o = oh * 128 + w * 32 + mt * 16 + quad * 4 + rg;
      float so = scale[o], bo = b2[o];
#pragma unroll
      for (int nt = 0; nt < 4; nt++) {
        int p = pt * 64 + nt * 16 + l16;
        long xo = ((long)b * C_ + o) * N_ + p;
        out[xo] = (acc[mt][nt][rg] + bo) * so + x[xo];
      }
    }
}

extern "C" void kernel_launch(void* const* d_in, const int* in_sizes, int n_in,
                              void* d_out, int out_size, void* d_ws, size_t ws_size,
                              hipStream_t stream) {
  const float* x     = (const float*)d_in[0];
  const float* W1    = (const float*)d_in[1];
  const float* b1    = (const float*)d_in[2];
  const float* W2    = (const float*)d_in[3];
  const float* b2    = (const float*)d_in[4];
  const float* scale = (const float*)d_in[5];
  float* outp = (float*)d_out;

  const size_t NE = (size_t)B_ * N_ * C2_;       // 4,194,304
  f16* Y    = (f16*)d_ws;                        // 8 MiB
  f16* Yt   = Y + NE;                            // 8 MiB
  f16* w1h  = Yt + NE;                           // 64 KiB
  f16* w2h  = w1h + 32768;                       // 64 KiB
  float* ls = (float*)(w2h + 32768);             // up to 3 x 32768 f32
  f16* Op   = (f16*)(ls + 3 * 32768);            // ns x 8 MiB split partials

  // choose split count from workspace size (constant across calls)
  size_t fixed = (size_t)((char*)Op - (char*)d_ws);
  int ns = 2;
  if (ws_size >= fixed + 3 * NE * sizeof(f16)) ns = 3;

  prep_kernel <<<dim3(128),       dim3(256), 0, stream>>>(W1, W2, w1h, w2h);
  conv1_kernel<<<dim3(8, 128),    dim3(256), 0, stream>>>(x, w1h, b1, Y, Yt);
  attn_kernel <<<dim3(8, 32, ns), dim3(256), 0, stream>>>(Y, Yt, Op, ls);
  conv2_kernel<<<dim3(8, 64, 2),  dim3(256), 0, stream>>>(Op, ls, w2h, b2, scale, x, outp, ns);
}